// Round 3
// baseline (309.759 us; speedup 1.0000x reference)
//
#include <hip/hip_runtime.h>

#define NN 512
#define DIN 64
#define DH 32
#define NB 64

typedef __attribute__((ext_vector_type(8))) short short8;
typedef __attribute__((ext_vector_type(4))) float f32x4;

__device__ __forceinline__ float bf2f(unsigned short u) {
    return __uint_as_float(((unsigned)u) << 16);
}
__device__ __forceinline__ unsigned short f2bf(float x) {
    unsigned u = __float_as_uint(x);
    u += 0x7FFF + ((u >> 16) & 1);
    return (unsigned short)(u >> 16);
}

__global__ __launch_bounds__(256) void zero_msgs(float* __restrict__ p) {
    // 32*512*32 floats = 524288; 512 blocks * 256 threads * 4 floats
    int i = (blockIdx.x * 256 + threadIdx.x) * 4;
    f32x4 z = {0.f, 0.f, 0.f, 0.f};
    *(f32x4*)(p + i) = z;
}

// One block per (head, batch). 256 threads.
__global__ __launch_bounds__(256) void attn_kernel(
    const float* __restrict__ in_g,    // [B,512,64] fp32
    const float* __restrict__ lin_g,   // [H,64,32]  fp32
    const float* __restrict__ asrc_g,  // [H,32]
    const float* __restrict__ atar_g,  // [H,32]
    float* __restrict__ msgs)          // [B,512,32] fp32 accum
{
    __shared__ unsigned short h_s[NN * 34];        // 34816 B (ch 0..31 = h bf16, ch32 = 1.0)
    __shared__ float PA[65 * 33];                  // prefix of e^s bucket sums
    __shared__ float PB[65 * 33];                  // prefix of e^{0.2s} bucket sums
    __shared__ float s_arr[NN], t_arr[NN], e1a[NN], e2a[NN], dinv_s[NN];
    __shared__ unsigned short blist[NN];           // bucket-ordered row list
    __shared__ int counts[NB], bstart[NB + 1], offs[NB];
    __shared__ float avec[64];                     // att_src[0..31], att_tar[32..63]
    __shared__ float wred[8];
    __shared__ float srange[2];                    // smin, invw

    const int t = threadIdx.x;
    const int lane = t & 63, wv = t >> 6;
    const int hIdx = blockIdx.x & 7, bIdx = blockIdx.x >> 3;

    if (t < 32) avec[t] = asrc_g[hIdx * 32 + t];
    else if (t < 64) avec[t] = atar_g[hIdx * 32 + (t - 32)];
    if (t < NB) counts[t] = 0;

    // ---------- P1: projection h = x[b] @ linear[h] via MFMA 16x16x32 bf16 ----------
    const int l15 = lane & 15, quad = lane >> 4;
    short8 bfrag[2][2];
    {
        const float* lp = lin_g + hIdx * (DIN * DH);
        for (int nt = 0; nt < 2; ++nt)
            for (int ks = 0; ks < 2; ++ks)
                for (int j = 0; j < 8; ++j)
                    bfrag[nt][ks][j] = (short)f2bf(lp[(ks * 32 + quad * 8 + j) * DH + l15 + nt * 16]);
    }
    const float* xb = in_g + (size_t)bIdx * (NN * DIN);
    for (int mi = 0; mi < 8; ++mi) {
        int mt = wv * 8 + mi;
        int row = mt * 16 + l15;
        const float* rp = xb + row * DIN + quad * 8;
        f32x4 x0 = *((const f32x4*)rp);
        f32x4 x1 = *((const f32x4*)(rp + 4));
        f32x4 x2 = *((const f32x4*)(rp + 32));
        f32x4 x3 = *((const f32x4*)(rp + 36));
        short8 a0, a1;
        for (int j = 0; j < 4; ++j) {
            a0[j]     = (short)f2bf(x0[j]);
            a0[4 + j] = (short)f2bf(x1[j]);
            a1[j]     = (short)f2bf(x2[j]);
            a1[4 + j] = (short)f2bf(x3[j]);
        }
        f32x4 c0 = {0.f, 0.f, 0.f, 0.f}, c1 = {0.f, 0.f, 0.f, 0.f};
        c0 = __builtin_amdgcn_mfma_f32_16x16x32_bf16(a0, bfrag[0][0], c0, 0, 0, 0);
        c0 = __builtin_amdgcn_mfma_f32_16x16x32_bf16(a1, bfrag[0][1], c0, 0, 0, 0);
        c1 = __builtin_amdgcn_mfma_f32_16x16x32_bf16(a0, bfrag[1][0], c1, 0, 0, 0);
        c1 = __builtin_amdgcn_mfma_f32_16x16x32_bf16(a1, bfrag[1][1], c1, 0, 0, 0);
        for (int r = 0; r < 4; ++r) {
            int m = mt * 16 + quad * 4 + r;
            h_s[m * 34 + l15]      = f2bf(c0[r]);
            h_s[m * 34 + l15 + 16] = f2bf(c1[r]);
        }
    }
    __syncthreads();

    // ---------- P2: e_src (s), e_tar (t), exps, min/max ----------
    float lmin = 1e30f, lmax = -1e30f;
    for (int rr = 0; rr < 2; ++rr) {
        int r = t + rr * 256;
        float ds = 0.f, dt = 0.f;
        for (int q = 0; q < 32; ++q) {
            float hv = bf2f(h_s[r * 34 + q]);
            ds += hv * avec[q];
            dt += hv * avec[32 + q];
        }
        h_s[r * 34 + 32] = 0x3F80;  // bf16 1.0 -> denominator channel
        s_arr[r] = ds; t_arr[r] = dt;
        e1a[r] = expf(ds); e2a[r] = expf(0.2f * ds);
        lmin = fminf(lmin, ds); lmax = fmaxf(lmax, ds);
    }
    for (int off = 32; off; off >>= 1) {
        lmin = fminf(lmin, __shfl_xor(lmin, off, 64));
        lmax = fmaxf(lmax, __shfl_xor(lmax, off, 64));
    }
    if (lane == 0) { wred[wv] = lmin; wred[4 + wv] = lmax; }
    __syncthreads();
    if (t == 0) {
        float mn = fminf(fminf(wred[0], wred[1]), fminf(wred[2], wred[3]));
        float mx = fmaxf(fmaxf(wred[4], wred[5]), fmaxf(wred[6], wred[7]));
        srange[0] = mn;
        srange[1] = (float)NB / fmaxf(mx - mn, 1e-12f);
    }
    __syncthreads();

    // ---------- P3: bucketize s_j (counting sort into bucket order) ----------
    const float smin = srange[0], invw = srange[1];
    int bidx_[2];
    for (int rr = 0; rr < 2; ++rr) {
        int r = t + rr * 256;
        float fb = (s_arr[r] - smin) * invw;
        fb = fminf(fmaxf(fb, 0.f), 63.f);
        int bkt = (int)fb;
        bidx_[rr] = bkt;
        atomicAdd(&counts[bkt], 1);
    }
    __syncthreads();
    if (t < NB) {
        int v = counts[t];
        for (int off = 1; off < NB; off <<= 1) {
            int u = __shfl_up(v, off, 64);
            if (t >= off) v += u;
        }
        bstart[t + 1] = v;
        if (t == 0) bstart[0] = 0;
    }
    __syncthreads();
    if (t < NB) offs[t] = bstart[t];
    __syncthreads();
    for (int rr = 0; rr < 2; ++rr) {
        int r = t + rr * 256;
        int pos = atomicAdd(&offs[bidx_[rr]], 1);
        blist[pos] = (unsigned short)r;
    }
    if (t < 33) { PA[t] = 0.f; PB[t] = 0.f; }
    __syncthreads();

    // ---------- P4: per-bucket weighted sums, then prefix over buckets ----------
    for (int rep = 0; rep < 9; ++rep) {
        int item = rep * 256 + t;
        if (item < NB * 33) {
            int bkt = item / 33, ch = item - bkt * 33;
            float a1 = 0.f, a2 = 0.f;
            int e = bstart[bkt + 1];
            for (int m = bstart[bkt]; m < e; ++m) {
                int j = blist[m];
                float hv = bf2f(h_s[j * 34 + ch]);
                a1 += e1a[j] * hv;
                a2 += e2a[j] * hv;
            }
            PA[(bkt + 1) * 33 + ch] = a1;
            PB[(bkt + 1) * 33 + ch] = a2;
        }
    }
    __syncthreads();
    // two-level in-place scan over rows 1..64 (8 groups of 8), 66 channels (A+B)
    for (int rep = 0; rep < 3; ++rep) {
        int item = rep * 256 + t;
        if (item < 528) {
            int g = item & 7, chh = item >> 3;
            float* T = (chh >= 33) ? PB : PA;
            int ch = (chh >= 33) ? chh - 33 : chh;
            float acc = 0.f;
            for (int b2 = g * 8 + 1; b2 <= g * 8 + 8; ++b2) {
                acc += T[b2 * 33 + ch];
                T[b2 * 33 + ch] = acc;
            }
        }
    }
    __syncthreads();
    if (t < 66) {
        float* T = (t >= 33) ? PB : PA;
        int ch = (t >= 33) ? t - 33 : t;
        for (int g = 1; g < 8; ++g) {
            float base = T[(g * 8) * 33 + ch];
            for (int b2 = g * 8 + 1; b2 <= g * 8 + 8; ++b2) T[b2 * 33 + ch] += base;
        }
    }
    __syncthreads();

    // ---------- P5: per-row softmax denominator ----------
    for (int rr = 0; rr < 2; ++rr) {
        int r = t + rr * 256;
        float ti = t_arr[r], c = -ti;
        float fb = floorf((c - smin) * invw);
        int bc;
        if (fb < 0.f) bc = -1;
        else bc = (int)fminf(fb, 63.f);
        float e1t = expf(ti), e2t = expf(0.2f * ti);
        float D = e1t * (PA[64 * 33 + 32] - PA[(bc + 1) * 33 + 32]);
        if (bc >= 0) {
            D += e2t * PB[bc * 33 + 32];
            int e = bstart[bc + 1];
            for (int m = bstart[bc]; m < e; ++m) {
                int j = blist[m];
                D += (s_arr[j] <= c) ? e2t * e2a[j] : e1t * e1a[j];
            }
        }
        D -= (s_arr[r] <= c) ? e2t * e2a[r] : e1t * e1a[r];  // remove self-edge
        dinv_s[r] = 0.125f / D;   // fold the 1/H head mean
    }
    __syncthreads();

    // ---------- P6: numerators + accumulate msgs ----------
    const int k = t & 31, ig = t >> 5;
    float* mrow = msgs + (size_t)bIdx * (NN * DH);
    for (int iter = 0; iter < 64; ++iter) {
        int i = iter * 8 + ig;
        float ti = t_arr[i], c = -ti;
        float fb = floorf((c - smin) * invw);
        int bc;
        if (fb < 0.f) bc = -1;
        else bc = (int)fminf(fb, 63.f);
        float e1t = expf(ti), e2t = expf(0.2f * ti);
        float acc = e1t * (PA[64 * 33 + k] - PA[(bc + 1) * 33 + k]);
        if (bc >= 0) {
            acc += e2t * PB[bc * 33 + k];
            int e = bstart[bc + 1];
            for (int m = bstart[bc]; m < e; ++m) {
                int j = blist[m];
                float w = (s_arr[j] <= c) ? e2t * e2a[j] : e1t * e1a[j];
                acc += w * bf2f(h_s[j * 34 + k]);
            }
        }
        float wd = (s_arr[i] <= c) ? e2t * e2a[i] : e1t * e1a[i];
        acc -= wd * bf2f(h_s[i * 34 + k]);   // self-edge
        atomicAdd(&mrow[i * 32 + k], acc * dinv_s[i]);
    }
}

// GRU-style gated update. 8 rows per block of 256 threads. All fp32.
__global__ __launch_bounds__(256) void gru_kernel(
    const float* __restrict__ in_g,
    const float* __restrict__ hid_g,
    const float* __restrict__ bias_g,
    const float* __restrict__ Whr, const float* __restrict__ Whi,
    const float* __restrict__ Whm,
    const float* __restrict__ Wir, const float* __restrict__ bir,
    const float* __restrict__ Wii, const float* __restrict__ bii,
    const float* __restrict__ Win, const float* __restrict__ bin_,
    const float* __restrict__ msgs,
    float* __restrict__ out_g)
{
    __shared__ float Wx[3 * DIN * DH];   // 24 KB
    __shared__ float Wh[3 * DH * DH];    // 12 KB
    __shared__ float bvec[4 * DH];
    __shared__ float xs[8 * DIN];
    __shared__ float msgv[8 * DH];

    const int t = threadIdx.x;
    const int k = t & 31, ig = t >> 5;
    const int rowbase = blockIdx.x * 8;
    const int row = rowbase + ig;

    for (int i = t; i < DIN * DH; i += 256) {
        Wx[i]                = Wir[i];
        Wx[DIN * DH + i]     = Wii[i];
        Wx[2 * DIN * DH + i] = Win[i];
    }
    for (int i = t; i < DH * DH; i += 256) {
        Wh[i]               = Whr[i];
        Wh[DH * DH + i]     = Whi[i];
        Wh[2 * DH * DH + i] = Whm[i];
    }
    if (t < 32) {
        bvec[t]      = bir[t];
        bvec[32 + t] = bii[t];
        bvec[64 + t] = bin_[t];
        bvec[96 + t] = bias_g[t];
    }
    for (int i = t; i < 8 * DIN; i += 256) xs[i] = in_g[(size_t)rowbase * DIN + i];
    __syncthreads();   // bvec/xs/Wx/Wh visible BEFORE any cross-thread read
    msgv[t] = tanhf(msgs[(size_t)row * DH + k] + bvec[96 + k]);
    __syncthreads();   // msgv visible across row groups

    float ar = 0.f, ai = 0.f, an = 0.f;
    for (int d = 0; d < DIN; ++d) {
        float xd = xs[ig * DIN + d];
        ar += xd * Wx[d * DH + k];
        ai += xd * Wx[DIN * DH + d * DH + k];
        an += xd * Wx[2 * DIN * DH + d * DH + k];
    }
    float hr = 0.f, hi = 0.f, hm = 0.f;
    for (int q = 0; q < DH; ++q) {
        float mv = msgv[ig * DH + q];
        hr += mv * Wh[q * DH + k];
        hi += mv * Wh[DH * DH + q * DH + k];
        hm += mv * Wh[2 * DH * DH + q * DH + k];
    }
    float mg = 1.f / (1.f + expf(-(ar + bvec[k] + hr)));
    float iG = 1.f / (1.f + expf(-(ai + bvec[32 + k] + hi)));
    float nn = tanhf(an + bvec[64 + k] + mg * hm);
    float ho = hid_g[(size_t)row * DH + k];
    float res = iG * nn + (1.f - iG) * ho;
    out_g[(size_t)row * DH + k] = res;
}

extern "C" void kernel_launch(void* const* d_in, const int* in_sizes, int n_in,
                              void* d_out, int out_size, void* d_ws, size_t ws_size,
                              hipStream_t stream)
{
    const float* inputs = (const float*)d_in[0];
    const float* hidden = (const float*)d_in[1];
    const float* linear = (const float*)d_in[2];
    const float* bias   = (const float*)d_in[3];
    const float* asrc   = (const float*)d_in[4];
    const float* atar   = (const float*)d_in[5];
    const float* Whr    = (const float*)d_in[6];
    const float* Whi    = (const float*)d_in[7];
    const float* Whm    = (const float*)d_in[8];
    const float* Wir    = (const float*)d_in[9];
    const float* bir    = (const float*)d_in[10];
    const float* Wii    = (const float*)d_in[11];
    const float* bii    = (const float*)d_in[12];
    const float* Win    = (const float*)d_in[13];
    const float* bin_   = (const float*)d_in[14];

    float* msgs = (float*)d_ws;                       // [32,512,32] fp32
    zero_msgs<<<dim3(512), dim3(256), 0, stream>>>(msgs);
    attn_kernel<<<dim3(256), dim3(256), 0, stream>>>(inputs, linear, asrc, atar, msgs);
    gru_kernel<<<dim3(2048), dim3(256), 0, stream>>>(inputs, hidden, bias,
                                                     Whr, Whi, Whm,
                                                     Wir, bir, Wii, bii, Win, bin_,
                                                     msgs, (float*)d_out);
}

// Round 4
// 136.321 us; speedup vs baseline: 2.2723x; 2.2723x over previous
//
#include <hip/hip_runtime.h>

#define NN 512
#define DIN 64
#define DH 32
#define HSTR 520   // h_t row stride in elements (pad: 260 dw == 4 mod 32, 16B-aligned)

typedef __attribute__((ext_vector_type(8))) short short8;
typedef __attribute__((ext_vector_type(4))) short short4v;
typedef __attribute__((ext_vector_type(4))) float f32x4;

__device__ __forceinline__ float bf2f(unsigned short u) {
    return __uint_as_float(((unsigned)u) << 16);
}
__device__ __forceinline__ unsigned short f2bf(float x) {
    unsigned u = __float_as_uint(x);
    u += 0x7FFF + ((u >> 16) & 1);
    return (unsigned short)(u >> 16);
}

__global__ __launch_bounds__(256) void zero_msgs(float* __restrict__ p) {
    int i = (blockIdx.x * 256 + threadIdx.x) * 4;
    f32x4 z = {0.f, 0.f, 0.f, 0.f};
    *(f32x4*)(p + i) = z;
}

// One block per (head, batch). 512 threads = 8 waves.
// Phase A: h = x @ W (MFMA), s/t via shuffle reduction of the MFMA epilogue.
// Phase B: numerator = W_att @ h via MFMA with A-fragments of w built in registers;
//          denominator accumulated per-lane from the same w values (fp32).
__global__ __launch_bounds__(512) void attn_kernel(
    const float* __restrict__ in_g,    // [B,512,64]
    const float* __restrict__ lin_g,   // [H,64,32]
    const float* __restrict__ asrc_g,  // [H,32]
    const float* __restrict__ atar_g,  // [H,32]
    float* __restrict__ msgs)          // [B,512,32] fp32 accum (atomic over heads)
{
    __shared__ unsigned short h_t[DH * HSTR];   // 33280 B: h_t[c*HSTR + m] = h[m][c] bf16
    __shared__ float s_arr[NN], e1s[NN], e2s[NN];   // j-side: s, e^s, e^{0.2s}
    __shared__ float cng[NN], e1t[NN], e2t[NN];     // i-side: -t, e^t, e^{0.2t}
    __shared__ float dinv[NN];

    const int t = threadIdx.x;
    const int lane = t & 63, wv = t >> 6;
    const int l15 = lane & 15, quad = lane >> 4;
    const int hIdx = blockIdx.x & 7, bIdx = blockIdx.x >> 3;

    // per-lane attention-vector elements (cols l15, l15+16)
    const float as_lo = asrc_g[hIdx * 32 + l15];
    const float as_hi = asrc_g[hIdx * 32 + l15 + 16];
    const float at_lo = atar_g[hIdx * 32 + l15];
    const float at_hi = atar_g[hIdx * 32 + l15 + 16];

    // ---------- Phase A: projection ----------
    short8 bfrag[2][2];
    {
        const float* lp = lin_g + hIdx * (DIN * DH);
        for (int nt = 0; nt < 2; ++nt)
            for (int ks = 0; ks < 2; ++ks)
                #pragma unroll
                for (int j = 0; j < 8; ++j)
                    bfrag[nt][ks][j] = (short)f2bf(lp[(ks * 32 + quad * 8 + j) * DH + l15 + nt * 16]);
    }
    const float* xb = in_g + (size_t)bIdx * (NN * DIN);
    for (int mi = 0; mi < 4; ++mi) {
        int mt = wv * 4 + mi;                 // 32 M-tiles of 16 rows over 8 waves
        int row = mt * 16 + l15;
        const float* rp = xb + row * DIN + quad * 8;
        f32x4 x0 = *((const f32x4*)rp);
        f32x4 x1 = *((const f32x4*)(rp + 4));
        f32x4 x2 = *((const f32x4*)(rp + 32));
        f32x4 x3 = *((const f32x4*)(rp + 36));
        short8 a0, a1;
        #pragma unroll
        for (int j = 0; j < 4; ++j) {
            a0[j]     = (short)f2bf(x0[j]);
            a0[4 + j] = (short)f2bf(x1[j]);
            a1[j]     = (short)f2bf(x2[j]);
            a1[4 + j] = (short)f2bf(x3[j]);
        }
        f32x4 c0 = {0.f, 0.f, 0.f, 0.f}, c1 = {0.f, 0.f, 0.f, 0.f};
        c0 = __builtin_amdgcn_mfma_f32_16x16x32_bf16(a0, bfrag[0][0], c0, 0, 0, 0);
        c0 = __builtin_amdgcn_mfma_f32_16x16x32_bf16(a1, bfrag[0][1], c0, 0, 0, 0);
        c1 = __builtin_amdgcn_mfma_f32_16x16x32_bf16(a0, bfrag[1][0], c1, 0, 0, 0);
        c1 = __builtin_amdgcn_mfma_f32_16x16x32_bf16(a1, bfrag[1][1], c1, 0, 0, 0);
        // store h transposed (bf16) + s/t partials
        float ps[4], pt[4];
        #pragma unroll
        for (int r = 0; r < 4; ++r) {
            int m = mt * 16 + quad * 4 + r;
            h_t[l15 * HSTR + m]        = f2bf(c0[r]);
            h_t[(l15 + 16) * HSTR + m] = f2bf(c1[r]);
            ps[r] = c0[r] * as_lo + c1[r] * as_hi;
            pt[r] = c0[r] * at_lo + c1[r] * at_hi;
        }
        // butterfly over the 16 l15-lanes (bits 0..3)
        #pragma unroll
        for (int off = 1; off <= 8; off <<= 1) {
            #pragma unroll
            for (int r = 0; r < 4; ++r) {
                ps[r] += __shfl_xor(ps[r], off, 64);
                pt[r] += __shfl_xor(pt[r], off, 64);
            }
        }
        if (l15 < 4) {
            int r = l15;
            int m = mt * 16 + quad * 4 + r;
            float s = ps[r], tt = pt[r];
            s_arr[m] = s;
            e1s[m] = expf(s);        e2s[m] = expf(0.2f * s);
            cng[m] = -tt;
            e1t[m] = expf(tt);       e2t[m] = expf(0.2f * tt);
        }
    }
    __syncthreads();

    // ---------- Phase B: numerator MFMA + fp32 denominator ----------
    float cn[4], t1[4], t2[4];
    int iR[4];
    #pragma unroll
    for (int rt = 0; rt < 4; ++rt) {
        int rw = (wv * 4 + rt) * 16 + l15;
        iR[rt] = rw;
        cn[rt] = cng[rw]; t1[rt] = e1t[rw]; t2[rt] = e2t[rw];
    }
    f32x4 acc[4][2];
    float dacc[4];
    #pragma unroll
    for (int rt = 0; rt < 4; ++rt) {
        acc[rt][0] = (f32x4){0.f, 0.f, 0.f, 0.f};
        acc[rt][1] = (f32x4){0.f, 0.f, 0.f, 0.f};
        dacc[rt] = 0.f;
    }

    for (int kb = 0; kb < 16; ++kb) {
        const int j0 = kb * 32 + quad * 8;
        f32x4 sv0 = *(const f32x4*)&s_arr[j0], sv1 = *(const f32x4*)&s_arr[j0 + 4];
        f32x4 ev0 = *(const f32x4*)&e1s[j0],   ev1 = *(const f32x4*)&e1s[j0 + 4];
        f32x4 fv0 = *(const f32x4*)&e2s[j0],   fv1 = *(const f32x4*)&e2s[j0 + 4];
        short8 b0 = *(const short8*)&h_t[l15 * HSTR + j0];
        short8 b1 = *(const short8*)&h_t[(l15 + 16) * HSTR + j0];
        #pragma unroll
        for (int rt = 0; rt < 4; ++rt) {
            const bool selfkb = (kb == ((wv * 4 + rt) >> 1));
            float w8[8];
            #pragma unroll
            for (int jj = 0; jj < 8; ++jj) {
                float sj = (jj < 4) ? sv0[jj & 3] : sv1[jj & 3];
                float e1 = (jj < 4) ? ev0[jj & 3] : ev1[jj & 3];
                float e2 = (jj < 4) ? fv0[jj & 3] : fv1[jj & 3];
                float w = (sj > cn[rt]) ? t1[rt] * e1 : t2[rt] * e2;
                if (selfkb && (j0 + jj == iR[rt])) w = 0.f;
                dacc[rt] += w;
                w8[jj] = w;
            }
            union { unsigned u[4]; short8 s8; } au;
            #pragma unroll
            for (int pp = 0; pp < 4; ++pp) {
                unsigned lo = __float_as_uint(w8[2 * pp])     + 0x8000u;
                unsigned hi = __float_as_uint(w8[2 * pp + 1]) + 0x8000u;
                au.u[pp] = (lo >> 16) | (hi & 0xffff0000u);
            }
            acc[rt][0] = __builtin_amdgcn_mfma_f32_16x16x32_bf16(au.s8, b0, acc[rt][0], 0, 0, 0);
            acc[rt][1] = __builtin_amdgcn_mfma_f32_16x16x32_bf16(au.s8, b1, acc[rt][1], 0, 0, 0);
        }
    }

    // denominator: reduce the 4 k-quads holding the same row (lanes share l15)
    #pragma unroll
    for (int rt = 0; rt < 4; ++rt) {
        float D = dacc[rt];
        D += __shfl_xor(D, 16, 64);
        D += __shfl_xor(D, 32, 64);
        if (quad == 0) dinv[iR[rt]] = 0.125f / D;   // fold 1/H; same-wave read below
    }

    float* mbase = msgs + (size_t)bIdx * (NN * DH);
    #pragma unroll
    for (int rt = 0; rt < 4; ++rt) {
        #pragma unroll
        for (int half = 0; half < 2; ++half) {
            #pragma unroll
            for (int r = 0; r < 4; ++r) {
                int row = (wv * 4 + rt) * 16 + quad * 4 + r;
                float dv = dinv[row];
                atomicAdd(&mbase[row * DH + half * 16 + l15], acc[rt][half][r] * dv);
            }
        }
    }
}

// GRU-style gated update. 256 blocks x 256 threads, 64 rows/block,
// thread = (k, rowgroup of 8 rows); W bf16 in LDS reused from registers.
__global__ __launch_bounds__(256) void gru_kernel(
    const float* __restrict__ in_g,
    const float* __restrict__ hid_g,
    const float* __restrict__ bias_g,
    const float* __restrict__ Whr, const float* __restrict__ Whi,
    const float* __restrict__ Whm,
    const float* __restrict__ Wir, const float* __restrict__ bir,
    const float* __restrict__ Wii, const float* __restrict__ bii,
    const float* __restrict__ Win, const float* __restrict__ bin_,
    const float* __restrict__ msgs,
    float* __restrict__ out_g)
{
    __shared__ float xs[64 * 100];              // cols 0..63 = x, 64..95 = tanh(msgs+bias)
    __shared__ unsigned short WtL[3 * 32 * 100];  // Wt[g][k][d] bf16, d-major (96 used)

    const int t = threadIdx.x;
    const int rowbase = blockIdx.x * 64;

    // stage x (4096 floats)
    for (int idx = t; idx < 1024; idx += 256) {
        int fi = idx * 4;
        int row = fi >> 6, d = fi & 63;
        f32x4 v = *(const f32x4*)&in_g[(size_t)(rowbase + row) * 64 + d];
        *(f32x4*)&xs[row * 100 + d] = v;
    }
    // stage msgv = tanh(msgs + bias) (2048 floats)
    for (int idx = t; idx < 2048; idx += 256) {
        int row = idx >> 5, k2 = idx & 31;
        xs[row * 100 + 64 + k2] = tanhf(msgs[(size_t)(rowbase + row) * 32 + k2] + bias_g[k2]);
    }
    // stage Wt bf16: g in {r,i,n/hm}, rows 0..63 from Wx, 64..95 from Wh
    for (int idx = t; idx < 9216; idx += 256) {
        int g = idx / 3072, rem = idx % 3072;
        int d = rem >> 5, k2 = rem & 31;
        float v;
        if (g == 0) v = (d < 64) ? Wir[d * 32 + k2] : Whr[(d - 64) * 32 + k2];
        else if (g == 1) v = (d < 64) ? Wii[d * 32 + k2] : Whi[(d - 64) * 32 + k2];
        else v = (d < 64) ? Win[d * 32 + k2] : Whm[(d - 64) * 32 + k2];
        WtL[(g * 32 + k2) * 100 + d] = f2bf(v);
    }
    __syncthreads();

    const int k = t & 31, rg = t >> 5;
    const unsigned short* wp0 = &WtL[(0 * 32 + k) * 100];
    const unsigned short* wp1 = &WtL[(1 * 32 + k) * 100];
    const unsigned short* wp2 = &WtL[(2 * 32 + k) * 100];

    float pr[8], pi[8], xn[8], hm[8];
    #pragma unroll
    for (int r = 0; r < 8; ++r) { pr[r] = 0.f; pi[r] = 0.f; xn[r] = 0.f; hm[r] = 0.f; }

    // x part: d in [0,64) -> gates r,i and xn
    for (int d0 = 0; d0 < 64; d0 += 4) {
        short4v wr4 = *(const short4v*)&wp0[d0];
        short4v wi4 = *(const short4v*)&wp1[d0];
        short4v wn4 = *(const short4v*)&wp2[d0];
        float wr[4], wi[4], wn[4];
        #pragma unroll
        for (int jj = 0; jj < 4; ++jj) {
            wr[jj] = bf2f((unsigned short)wr4[jj]);
            wi[jj] = bf2f((unsigned short)wi4[jj]);
            wn[jj] = bf2f((unsigned short)wn4[jj]);
        }
        #pragma unroll
        for (int r = 0; r < 8; ++r) {
            f32x4 xv = *(const f32x4*)&xs[(rg * 8 + r) * 100 + d0];
            #pragma unroll
            for (int jj = 0; jj < 4; ++jj) {
                pr[r] += xv[jj] * wr[jj];
                pi[r] += xv[jj] * wi[jj];
                xn[r] += xv[jj] * wn[jj];
            }
        }
    }
    // msg part: d in [64,96) -> gates r,i and hm
    for (int d0 = 64; d0 < 96; d0 += 4) {
        short4v wr4 = *(const short4v*)&wp0[d0];
        short4v wi4 = *(const short4v*)&wp1[d0];
        short4v wn4 = *(const short4v*)&wp2[d0];
        float wr[4], wi[4], wn[4];
        #pragma unroll
        for (int jj = 0; jj < 4; ++jj) {
            wr[jj] = bf2f((unsigned short)wr4[jj]);
            wi[jj] = bf2f((unsigned short)wi4[jj]);
            wn[jj] = bf2f((unsigned short)wn4[jj]);
        }
        #pragma unroll
        for (int r = 0; r < 8; ++r) {
            f32x4 xv = *(const f32x4*)&xs[(rg * 8 + r) * 100 + d0];
            #pragma unroll
            for (int jj = 0; jj < 4; ++jj) {
                pr[r] += xv[jj] * wr[jj];
                pi[r] += xv[jj] * wi[jj];
                hm[r] += xv[jj] * wn[jj];
            }
        }
    }

    const float bir_k = bir[k], bii_k = bii[k], bin_k = bin_[k];
    #pragma unroll
    for (int r = 0; r < 8; ++r) {
        int row = rowbase + rg * 8 + r;
        float m  = 1.f / (1.f + expf(-(pr[r] + bir_k)));
        float ig = 1.f / (1.f + expf(-(pi[r] + bii_k)));
        float nn = tanhf(xn[r] + bin_k + m * hm[r]);
        float ho = hid_g[(size_t)row * 32 + k];
        out_g[(size_t)row * 32 + k] = ig * nn + (1.f - ig) * ho;
    }
}

extern "C" void kernel_launch(void* const* d_in, const int* in_sizes, int n_in,
                              void* d_out, int out_size, void* d_ws, size_t ws_size,
                              hipStream_t stream)
{
    const float* inputs = (const float*)d_in[0];
    const float* hidden = (const float*)d_in[1];
    const float* linear = (const float*)d_in[2];
    const float* bias   = (const float*)d_in[3];
    const float* asrc   = (const float*)d_in[4];
    const float* atar   = (const float*)d_in[5];
    const float* Whr    = (const float*)d_in[6];
    const float* Whi    = (const float*)d_in[7];
    const float* Whm    = (const float*)d_in[8];
    const float* Wir    = (const float*)d_in[9];
    const float* bir    = (const float*)d_in[10];
    const float* Wii    = (const float*)d_in[11];
    const float* bii    = (const float*)d_in[12];
    const float* Win    = (const float*)d_in[13];
    const float* bin_   = (const float*)d_in[14];

    float* msgs = (float*)d_ws;   // [32,512,32] fp32
    zero_msgs<<<dim3(512), dim3(256), 0, stream>>>(msgs);
    attn_kernel<<<dim3(256), dim3(512), 0, stream>>>(inputs, linear, asrc, atar, msgs);
    gru_kernel<<<dim3(256), dim3(256), 0, stream>>>(inputs, hidden, bias,
                                                    Whr, Whi, Whm,
                                                    Wir, bir, Wii, bii, Win, bin_,
                                                    msgs, (float*)d_out);
}

// Round 5
// 133.424 us; speedup vs baseline: 2.3216x; 1.0217x over previous
//
#include <hip/hip_runtime.h>

#define NN 512
#define DIN 64
#define DH 32
#define HSTR 520   // h_t row stride (pad: 260 dw == 4 mod 32, keeps 16B alignment)

typedef __attribute__((ext_vector_type(8))) short short8;
typedef __attribute__((ext_vector_type(4))) short short4v;
typedef __attribute__((ext_vector_type(4))) float f32x4;

__device__ __forceinline__ float bf2f(unsigned short u) {
    return __uint_as_float(((unsigned)u) << 16);
}
__device__ __forceinline__ unsigned short f2bf(float x) {
    unsigned u = __float_as_uint(x);
    u += 0x7FFF + ((u >> 16) & 1);
    return (unsigned short)(u >> 16);
}

// One block per (head, batch). 512 threads = 8 waves.
// Writes its own head-slice msgs8[blockIdx.x][512][32] — NO atomics.
__global__ __launch_bounds__(512) void attn_kernel(
    const float* __restrict__ in_g,    // [B,512,64]
    const float* __restrict__ lin_g,   // [H,64,32]
    const float* __restrict__ asrc_g,  // [H,32]
    const float* __restrict__ atar_g,  // [H,32]
    float* __restrict__ msgs8)         // [B*8][512][32] fp32, slice = blockIdx.x
{
    __shared__ unsigned short h_t[DH * HSTR];       // 33280 B: h_t[c*HSTR + m] = h[m][c]
    __shared__ float s_arr[NN], e1s[NN], e2s[NN];   // j-side: s, e^s, e^{0.2s}
    __shared__ float cng[NN], e1t[NN], e2t[NN];     // i-side: -t, e^t, e^{0.2t}
    __shared__ float dinv[NN];

    const int t = threadIdx.x;
    const int lane = t & 63, wv = t >> 6;
    const int l15 = lane & 15, quad = lane >> 4;
    const int hIdx = blockIdx.x & 7, bIdx = blockIdx.x >> 3;

    const float as_lo = asrc_g[hIdx * 32 + l15];
    const float as_hi = asrc_g[hIdx * 32 + l15 + 16];
    const float at_lo = atar_g[hIdx * 32 + l15];
    const float at_hi = atar_g[hIdx * 32 + l15 + 16];

    // ---------- Phase A: projection h = x @ W via MFMA ----------
    short8 bfrag[2][2];
    {
        const float* lp = lin_g + hIdx * (DIN * DH);
        for (int nt = 0; nt < 2; ++nt)
            for (int ks = 0; ks < 2; ++ks)
                #pragma unroll
                for (int j = 0; j < 8; ++j)
                    bfrag[nt][ks][j] = (short)f2bf(lp[(ks * 32 + quad * 8 + j) * DH + l15 + nt * 16]);
    }
    const float* xb = in_g + (size_t)bIdx * (NN * DIN);
    for (int mi = 0; mi < 4; ++mi) {
        int mt = wv * 4 + mi;
        int row = mt * 16 + l15;
        const float* rp = xb + row * DIN + quad * 8;
        f32x4 x0 = *((const f32x4*)rp);
        f32x4 x1 = *((const f32x4*)(rp + 4));
        f32x4 x2 = *((const f32x4*)(rp + 32));
        f32x4 x3 = *((const f32x4*)(rp + 36));
        short8 a0, a1;
        #pragma unroll
        for (int j = 0; j < 4; ++j) {
            a0[j]     = (short)f2bf(x0[j]);
            a0[4 + j] = (short)f2bf(x1[j]);
            a1[j]     = (short)f2bf(x2[j]);
            a1[4 + j] = (short)f2bf(x3[j]);
        }
        f32x4 c0 = {0.f, 0.f, 0.f, 0.f}, c1 = {0.f, 0.f, 0.f, 0.f};
        c0 = __builtin_amdgcn_mfma_f32_16x16x32_bf16(a0, bfrag[0][0], c0, 0, 0, 0);
        c0 = __builtin_amdgcn_mfma_f32_16x16x32_bf16(a1, bfrag[0][1], c0, 0, 0, 0);
        c1 = __builtin_amdgcn_mfma_f32_16x16x32_bf16(a0, bfrag[1][0], c1, 0, 0, 0);
        c1 = __builtin_amdgcn_mfma_f32_16x16x32_bf16(a1, bfrag[1][1], c1, 0, 0, 0);
        float ps[4], pt[4];
        #pragma unroll
        for (int r = 0; r < 4; ++r) {
            int m = mt * 16 + quad * 4 + r;
            h_t[l15 * HSTR + m]        = f2bf(c0[r]);
            h_t[(l15 + 16) * HSTR + m] = f2bf(c1[r]);
            ps[r] = c0[r] * as_lo + c1[r] * as_hi;
            pt[r] = c0[r] * at_lo + c1[r] * at_hi;
        }
        #pragma unroll
        for (int off = 1; off <= 8; off <<= 1) {
            #pragma unroll
            for (int r = 0; r < 4; ++r) {
                ps[r] += __shfl_xor(ps[r], off, 64);
                pt[r] += __shfl_xor(pt[r], off, 64);
            }
        }
        if (l15 < 4) {
            int r = l15;
            int m = mt * 16 + quad * 4 + r;
            float s = ps[r], tt = pt[r];
            s_arr[m] = s;
            e1s[m] = expf(s);   e2s[m] = expf(0.2f * s);
            cng[m] = -tt;
            e1t[m] = expf(tt);  e2t[m] = expf(0.2f * tt);
        }
    }
    __syncthreads();

    // ---------- Phase B: numerator MFMA (w built in-register) + fp32 denominator ----------
    float cn[4], t1[4], t2[4];
    int iR[4];
    #pragma unroll
    for (int rt = 0; rt < 4; ++rt) {
        int rw = (wv * 4 + rt) * 16 + l15;
        iR[rt] = rw;
        cn[rt] = cng[rw]; t1[rt] = e1t[rw]; t2[rt] = e2t[rw];
    }
    f32x4 acc[4][2];
    float dacc[4];
    #pragma unroll
    for (int rt = 0; rt < 4; ++rt) {
        acc[rt][0] = (f32x4){0.f, 0.f, 0.f, 0.f};
        acc[rt][1] = (f32x4){0.f, 0.f, 0.f, 0.f};
        dacc[rt] = 0.f;
    }

    for (int kb = 0; kb < 16; ++kb) {
        const int j0 = kb * 32 + quad * 8;
        f32x4 sv0 = *(const f32x4*)&s_arr[j0], sv1 = *(const f32x4*)&s_arr[j0 + 4];
        f32x4 ev0 = *(const f32x4*)&e1s[j0],   ev1 = *(const f32x4*)&e1s[j0 + 4];
        f32x4 fv0 = *(const f32x4*)&e2s[j0],   fv1 = *(const f32x4*)&e2s[j0 + 4];
        short8 b0 = *(const short8*)&h_t[l15 * HSTR + j0];
        short8 b1 = *(const short8*)&h_t[(l15 + 16) * HSTR + j0];
        #pragma unroll
        for (int rt = 0; rt < 4; ++rt) {
            const bool selfkb = (kb == ((wv * 4 + rt) >> 1));
            float w8[8];
            #pragma unroll
            for (int jj = 0; jj < 8; ++jj) {
                float sj = (jj < 4) ? sv0[jj & 3] : sv1[jj & 3];
                float e1 = (jj < 4) ? ev0[jj & 3] : ev1[jj & 3];
                float e2 = (jj < 4) ? fv0[jj & 3] : fv1[jj & 3];
                float w = (sj > cn[rt]) ? t1[rt] * e1 : t2[rt] * e2;
                if (selfkb && (j0 + jj == iR[rt])) w = 0.f;
                dacc[rt] += w;
                w8[jj] = w;
            }
            union { unsigned u[4]; short8 s8; } au;
            #pragma unroll
            for (int pp = 0; pp < 4; ++pp) {
                unsigned lo = __float_as_uint(w8[2 * pp])     + 0x8000u;
                unsigned hi = __float_as_uint(w8[2 * pp + 1]) + 0x8000u;
                au.u[pp] = (lo >> 16) | (hi & 0xffff0000u);
            }
            acc[rt][0] = __builtin_amdgcn_mfma_f32_16x16x32_bf16(au.s8, b0, acc[rt][0], 0, 0, 0);
            acc[rt][1] = __builtin_amdgcn_mfma_f32_16x16x32_bf16(au.s8, b1, acc[rt][1], 0, 0, 0);
        }
    }

    // denominator: reduce the 4 quads (same row lives in lanes sharing l15)
    #pragma unroll
    for (int rt = 0; rt < 4; ++rt) {
        float D = dacc[rt];
        D += __shfl_xor(D, 16, 64);
        D += __shfl_xor(D, 32, 64);
        if (quad == 0) dinv[iR[rt]] = 0.125f / D;   // fold 1/H; same-wave read below
    }

    float* mbase = msgs8 + (size_t)blockIdx.x * (NN * DH);
    #pragma unroll
    for (int rt = 0; rt < 4; ++rt) {
        #pragma unroll
        for (int half = 0; half < 2; ++half) {
            #pragma unroll
            for (int r = 0; r < 4; ++r) {
                int row = (wv * 4 + rt) * 16 + quad * 4 + r;
                mbase[row * DH + half * 16 + l15] = acc[rt][half][r] * dinv[row];
            }
        }
    }
}

// GRU-style gated update. 256 blocks x 256 threads, 64 rows/block.
// Sums the 8 head slices of msgs8 while staging msgv.
__global__ __launch_bounds__(256) void gru_kernel(
    const float* __restrict__ in_g,
    const float* __restrict__ hid_g,
    const float* __restrict__ bias_g,
    const float* __restrict__ Whr, const float* __restrict__ Whi,
    const float* __restrict__ Whm,
    const float* __restrict__ Wir, const float* __restrict__ bir,
    const float* __restrict__ Wii, const float* __restrict__ bii,
    const float* __restrict__ Win, const float* __restrict__ bin_,
    const float* __restrict__ msgs8,   // [B*8][512][32], slice = b*8+h
    float* __restrict__ out_g)
{
    __shared__ float xs[64 * 100];                // cols 0..63 = x, 64..95 = tanh(msum+bias)
    __shared__ unsigned short WtL[3 * 32 * 100];  // Wt[g][k][d] bf16 (96 d's used)

    const int t = threadIdx.x;
    const int rowbase = blockIdx.x * 64;
    const int bslice = blockIdx.x >> 3;           // batch of this block (64 | 512)
    const int r0 = (blockIdx.x & 7) * 64;         // row offset within batch

    for (int idx = t; idx < 1024; idx += 256) {
        int fi = idx * 4;
        int row = fi >> 6, d = fi & 63;
        f32x4 v = *(const f32x4*)&in_g[(size_t)(rowbase + row) * 64 + d];
        *(f32x4*)&xs[row * 100 + d] = v;
    }
    // msgv = tanh(sum_h msgs8[b*8+h] + bias)
    for (int idx = t; idx < 2048; idx += 256) {
        int row = idx >> 5, k2 = idx & 31;
        size_t base = (size_t)bslice * (8 * NN * DH) + (size_t)(r0 + row) * DH + k2;
        float s = 0.f;
        #pragma unroll
        for (int h = 0; h < 8; ++h) s += msgs8[base + (size_t)h * (NN * DH)];
        xs[row * 100 + 64 + k2] = tanhf(s + bias_g[k2]);
    }
    for (int idx = t; idx < 9216; idx += 256) {
        int g = idx / 3072, rem = idx % 3072;
        int d = rem >> 5, k2 = rem & 31;
        float v;
        if (g == 0) v = (d < 64) ? Wir[d * 32 + k2] : Whr[(d - 64) * 32 + k2];
        else if (g == 1) v = (d < 64) ? Wii[d * 32 + k2] : Whi[(d - 64) * 32 + k2];
        else v = (d < 64) ? Win[d * 32 + k2] : Whm[(d - 64) * 32 + k2];
        WtL[(g * 32 + k2) * 100 + d] = f2bf(v);
    }
    __syncthreads();

    const int k = t & 31, rg = t >> 5;
    const unsigned short* wp0 = &WtL[(0 * 32 + k) * 100];
    const unsigned short* wp1 = &WtL[(1 * 32 + k) * 100];
    const unsigned short* wp2 = &WtL[(2 * 32 + k) * 100];

    float pr[8], pi[8], xn[8], hm[8];
    #pragma unroll
    for (int r = 0; r < 8; ++r) { pr[r] = 0.f; pi[r] = 0.f; xn[r] = 0.f; hm[r] = 0.f; }

    for (int d0 = 0; d0 < 64; d0 += 4) {
        short4v wr4 = *(const short4v*)&wp0[d0];
        short4v wi4 = *(const short4v*)&wp1[d0];
        short4v wn4 = *(const short4v*)&wp2[d0];
        float wr[4], wi[4], wn[4];
        #pragma unroll
        for (int jj = 0; jj < 4; ++jj) {
            wr[jj] = bf2f((unsigned short)wr4[jj]);
            wi[jj] = bf2f((unsigned short)wi4[jj]);
            wn[jj] = bf2f((unsigned short)wn4[jj]);
        }
        #pragma unroll
        for (int r = 0; r < 8; ++r) {
            f32x4 xv = *(const f32x4*)&xs[(rg * 8 + r) * 100 + d0];
            #pragma unroll
            for (int jj = 0; jj < 4; ++jj) {
                pr[r] += xv[jj] * wr[jj];
                pi[r] += xv[jj] * wi[jj];
                xn[r] += xv[jj] * wn[jj];
            }
        }
    }
    for (int d0 = 64; d0 < 96; d0 += 4) {
        short4v wr4 = *(const short4v*)&wp0[d0];
        short4v wi4 = *(const short4v*)&wp1[d0];
        short4v wn4 = *(const short4v*)&wp2[d0];
        float wr[4], wi[4], wn[4];
        #pragma unroll
        for (int jj = 0; jj < 4; ++jj) {
            wr[jj] = bf2f((unsigned short)wr4[jj]);
            wi[jj] = bf2f((unsigned short)wi4[jj]);
            wn[jj] = bf2f((unsigned short)wn4[jj]);
        }
        #pragma unroll
        for (int r = 0; r < 8; ++r) {
            f32x4 xv = *(const f32x4*)&xs[(rg * 8 + r) * 100 + d0];
            #pragma unroll
            for (int jj = 0; jj < 4; ++jj) {
                pr[r] += xv[jj] * wr[jj];
                pi[r] += xv[jj] * wi[jj];
                hm[r] += xv[jj] * wn[jj];
            }
        }
    }

    const float bir_k = bir[k], bii_k = bii[k], bin_k = bin_[k];
    #pragma unroll
    for (int r = 0; r < 8; ++r) {
        int row = rowbase + rg * 8 + r;
        float m  = 1.f / (1.f + expf(-(pr[r] + bir_k)));
        float ig = 1.f / (1.f + expf(-(pi[r] + bii_k)));
        float nn = tanhf(xn[r] + bin_k + m * hm[r]);
        float ho = hid_g[(size_t)row * 32 + k];
        out_g[(size_t)row * 32 + k] = ig * nn + (1.f - ig) * ho;
    }
}

extern "C" void kernel_launch(void* const* d_in, const int* in_sizes, int n_in,
                              void* d_out, int out_size, void* d_ws, size_t ws_size,
                              hipStream_t stream)
{
    const float* inputs = (const float*)d_in[0];
    const float* hidden = (const float*)d_in[1];
    const float* linear = (const float*)d_in[2];
    const float* bias   = (const float*)d_in[3];
    const float* asrc   = (const float*)d_in[4];
    const float* atar   = (const float*)d_in[5];
    const float* Whr    = (const float*)d_in[6];
    const float* Whi    = (const float*)d_in[7];
    const float* Whm    = (const float*)d_in[8];
    const float* Wir    = (const float*)d_in[9];
    const float* bir    = (const float*)d_in[10];
    const float* Wii    = (const float*)d_in[11];
    const float* bii    = (const float*)d_in[12];
    const float* Win    = (const float*)d_in[13];
    const float* bin_   = (const float*)d_in[14];

    float* msgs8 = (float*)d_ws;   // [B*8][512][32] fp32, 16 MB
    attn_kernel<<<dim3(256), dim3(512), 0, stream>>>(inputs, linear, asrc, atar, msgs8);
    gru_kernel<<<dim3(256), dim3(256), 0, stream>>>(inputs, hidden, bias,
                                                    Whr, Whi, Whm,
                                                    Wir, bir, Wii, bii, Win, bin_,
                                                    msgs8, (float*)d_out);
}